// Round 1
// baseline (714.277 us; speedup 1.0000x reference)
//
#include <hip/hip_runtime.h>
#include <math.h>

#define N_OBS_C  1000000
#define NDIM     8192
#define RANK_C   64

#define E_BLOCKS 1024            // energy blocks (bid % 3 == 0)
#define S_BLOCKS 2048            // 2 matrices * 64 i-tiles * 16 j-chunks (128x512 each)

typedef __attribute__((ext_vector_type(8))) short bf16x8;
typedef __attribute__((ext_vector_type(4))) float f32x4;

// round-to-nearest-even f32 -> bf16 bits
__device__ __forceinline__ unsigned short f2bf(float f) {
  union { float f; unsigned int u; } x; x.f = f;
  unsigned int u = x.u;
  unsigned int r = (u + 0x7fffu + ((u >> 16) & 1u)) >> 16;
  return (unsigned short)r;
}

// ---------------------------------------------------------------------------
// Prep (verified): Vt[n][r] = V[r][n] (f32) + bf16 copies Ub, Vtb.
// ---------------------------------------------------------------------------
__global__ void prep_kernel(const float* __restrict__ V, const float* __restrict__ U,
                            float* __restrict__ Vt, unsigned short* __restrict__ Ub,
                            unsigned short* __restrict__ Vtb) {
  int b = blockIdx.x, t = threadIdx.x;
  if (b < 128) {
    __shared__ float tile[64][65];
    int c0 = b * 64;
#pragma unroll
    for (int i = 0; i < 16; ++i) {
      int idx = i * 256 + t;
      int r = idx >> 6, c = idx & 63;
      tile[r][c] = V[r * NDIM + c0 + c];
    }
    __syncthreads();
#pragma unroll
    for (int i = 0; i < 16; ++i) {
      int idx = i * 256 + t;
      int n = idx >> 6, r = idx & 63;
      float v = tile[r][n];
      Vt[(c0 + n) * RANK_C + r]  = v;
      Vtb[(c0 + n) * RANK_C + r] = f2bf(v);
    }
  } else {
    int nt  = 64 * 256;
    int tid = (b - 128) * 256 + t;
    for (int i = tid; i < NDIM * RANK_C; i += nt)
      Ub[i] = f2bf(U[i]);
  }
}

__device__ __forceinline__ void block_reduce_atomic(float v, float* out) {
#pragma unroll
  for (int off = 32; off > 0; off >>= 1) v += __shfl_down(v, off, 64);
  __shared__ float wsum[4];
  int w = threadIdx.x >> 6;
  if ((threadIdx.x & 63) == 0) wsum[w] = v;
  __syncthreads();
  if (threadIdx.x == 0) atomicAdd(out, wsum[0] + wsum[1] + wsum[2] + wsum[3]);
}

// ---------------------------------------------------------------------------
// Fused main kernel, barrier-free S path.
//   bid % 3 == 0  -> energy gather block (1024 total)
//   else          -> S quadratic-form block: 128x512 chunk of S_U or S_V.
// S path exploits G = A.A^T symmetry: mfma(bfr, af) yields the G^T fragment
// whose C-layout (row=quad*4+reg, col=lcol) pairs directly with a dwordx4
// row-major load of S -> no LDS transpose, no barriers.
// ---------------------------------------------------------------------------
__global__ void __launch_bounds__(256, 4)
main_kernel(const float* __restrict__ vals, const int* __restrict__ rows,
            const int* __restrict__ cols, const float* __restrict__ U,
            const float* __restrict__ sigma, const float* __restrict__ S_U,
            const float* __restrict__ S_V, const float* __restrict__ Vt,
            const unsigned short* __restrict__ Ub,
            const unsigned short* __restrict__ Vtb, float* __restrict__ out) {
  int bid = blockIdx.x;
  int t = threadIdx.x;

  if (bid % 3 == 0) {
    // ---------------- energy term ----------------
    float s2 = sigma[0] * sigma[0];
    float local = 0.f;
    const int estride = E_BLOCKS * 256;
    int n = (bid / 3) * 256 + t;
    if (n < N_OBS_C) {
      int r = rows[n], c = cols[n];
      float v = vals[n];
      for (;;) {
        // prefetch next iteration's indices so they overlap the gathers
        int nn = n + estride;
        bool more = (nn < N_OBS_C);
        int rn = 0, cn = 0; float vn = 0.f;
        if (more) { rn = rows[nn]; cn = cols[nn]; vn = vals[nn]; }

        const f32x4* up = (const f32x4*)(U  + (size_t)r * RANK_C);
        const f32x4* vp = (const f32x4*)(Vt + (size_t)c * RANK_C);
        float d0 = 0.f, d1 = 0.f, d2 = 0.f, d3 = 0.f;
#pragma unroll
        for (int k = 0; k < 16; k += 4) {
          f32x4 a0 = up[k],     b0 = vp[k];
          f32x4 a1 = up[k + 1], b1 = vp[k + 1];
          f32x4 a2 = up[k + 2], b2 = vp[k + 2];
          f32x4 a3 = up[k + 3], b3 = vp[k + 3];
          d0 += a0[0]*b0[0] + a0[1]*b0[1] + a0[2]*b0[2] + a0[3]*b0[3];
          d1 += a1[0]*b1[0] + a1[1]*b1[1] + a1[2]*b1[2] + a1[3]*b1[3];
          d2 += a2[0]*b2[0] + a2[1]*b2[1] + a2[2]*b2[2] + a2[3]*b2[3];
          d3 += a3[0]*b3[0] + a3[1]*b3[1] + a3[2]*b3[2] + a3[3]*b3[3];
        }
        float e = v - ((d0 + d1) + (d2 + d3));
        local += e * e;
        if (!more) break;
        n = nn; r = rn; c = cn; v = vn;
      }
    }
    local *= 1.0f / (2.0f * s2);
    if (bid == 0 && t == 0) local += (float)N_OBS_C * logf(s2);
    block_reduce_atomic(local, out);
  } else {
    // ---------------- S quadratic-form chunk ----------------
    int sb = (bid / 3) * 2 + (bid % 3) - 1;   // 0..2047
    const float* S; const unsigned short* A;
    if (sb < S_BLOCKS / 2) { S = S_U; A = Ub; }
    else                   { S = S_V; A = Vtb; sb -= S_BLOCKS / 2; }
    int ti0 = (sb >> 4) * 128;   // chunk row origin (64 i-tiles)
    int j0  = (sb & 15) * 512;   // chunk col origin (16 chunks of 512)

    int w = t >> 6, lane = t & 63, quad = lane >> 4, lcol = lane & 15;
    int r0 = ti0 + w * 32;       // this wave's 32-row strip

    // A fragments for the strip rows: hoisted for the whole chunk
    bf16x8 af[2][2];
#pragma unroll
    for (int ti = 0; ti < 2; ++ti)
#pragma unroll
      for (int kh = 0; kh < 2; ++kh)
        af[ti][kh] = *(const bf16x8*)(A + (size_t)(r0 + ti * 16 + lcol) * RANK_C +
                                      kh * 32 + quad * 8);

    // S base: row (r0 + lcol), col (j0 + quad*4); fragment (ti,tj,hh) adds
    // ti*16 rows and hh*64 + tj*16 cols -> dwordx4 = the 4 reg elements.
    const float* Sb = S + (size_t)(r0 + lcol) * NDIM + j0 + quad * 4;
    f32x4 sum = {0.f, 0.f, 0.f, 0.f};

#pragma unroll 1
    for (int hh = 0; hh < 8; ++hh) {       // 8 slabs of 64 cols
      int cb = j0 + hh * 64;
      // B fragments (slab cols as rows of A) -- L2-resident, issued first
      bf16x8 bfr[4][2];
#pragma unroll
      for (int tj = 0; tj < 4; ++tj)
#pragma unroll
        for (int kh = 0; kh < 2; ++kh)
          bfr[tj][kh] = *(const bf16x8*)(A + (size_t)(cb + tj * 16 + lcol) * RANK_C +
                                         kh * 32 + quad * 8);
      // S slab: 8 independent dwordx4 loads (1 KB/instr), in flight under MFMA
      f32x4 sv[2][4];
#pragma unroll
      for (int ti = 0; ti < 2; ++ti)
#pragma unroll
        for (int tj = 0; tj < 4; ++tj)
          sv[ti][tj] = *(const f32x4*)(Sb + (size_t)(ti * 16) * NDIM + hh * 64 + tj * 16);
      // G^T fragments via swapped operands, consumed element-wise vs S
#pragma unroll
      for (int ti = 0; ti < 2; ++ti)
#pragma unroll
        for (int tj = 0; tj < 4; ++tj) {
          f32x4 z = {0.f, 0.f, 0.f, 0.f};
          z = __builtin_amdgcn_mfma_f32_16x16x32_bf16(bfr[tj][0], af[ti][0], z, 0, 0, 0);
          z = __builtin_amdgcn_mfma_f32_16x16x32_bf16(bfr[tj][1], af[ti][1], z, 0, 0, 0);
          sum += z * sv[ti][tj];
        }
    }
    float p = (sum[0] + sum[1]) + (sum[2] + sum[3]);
    block_reduce_atomic(0.5f * p, out);
  }
}

extern "C" void kernel_launch(void* const* d_in, const int* in_sizes, int n_in,
                              void* d_out, int out_size, void* d_ws, size_t ws_size,
                              hipStream_t stream) {
  const float* vals  = (const float*)d_in[0];
  const int*   rows  = (const int*)  d_in[1];
  const int*   cols  = (const int*)  d_in[2];
  const float* U     = (const float*)d_in[3];
  const float* V     = (const float*)d_in[4];
  const float* sigma = (const float*)d_in[5];
  const float* S_U   = (const float*)d_in[6];
  const float* S_V   = (const float*)d_in[7];
  float* out = (float*)d_out;

  char* ws = (char*)d_ws;
  float*          Vt  = (float*)ws;                                  // 2 MB
  unsigned short* Ub  = (unsigned short*)(ws + 2u * 1024 * 1024);    // 1 MB
  unsigned short* Vtb = (unsigned short*)(ws + 3u * 1024 * 1024);    // 1 MB

  hipMemsetAsync(d_out, 0, sizeof(float), stream);
  prep_kernel<<<192, 256, 0, stream>>>(V, U, Vt, Ub, Vtb);
  // 1024 energy blocks interleaved 1-in-3 with 2048 S-chunk blocks
  main_kernel<<<E_BLOCKS + S_BLOCKS, 256, 0, stream>>>(vals, rows, cols, U, sigma,
                                                       S_U, S_V, Vt, Ub, Vtb, out);
}

// Round 2
// 626.587 us; speedup vs baseline: 1.1399x; 1.1399x over previous
//
#include <hip/hip_runtime.h>
#include <math.h>

#define N_OBS_C  1000000
#define NDIM     8192
#define RANK_C   64

#define E_BLOCKS 1024            // energy blocks (bid % 3 == 0)
#define S_BLOCKS 2048            // 2 matrices * 64 i-tiles * 16 j-chunks (128x512 each)

typedef __attribute__((ext_vector_type(8))) short bf16x8;
typedef __attribute__((ext_vector_type(4))) float f32x4;

// round-to-nearest-even f32 -> bf16 bits
__device__ __forceinline__ unsigned short f2bf(float f) {
  union { float f; unsigned int u; } x; x.f = f;
  unsigned int u = x.u;
  unsigned int r = (u + 0x7fffu + ((u >> 16) & 1u)) >> 16;
  return (unsigned short)r;
}

// ---------------------------------------------------------------------------
// Prep (verified): Vt[n][r] = V[r][n] (f32) + bf16 copies Ub, Vtb.
// ---------------------------------------------------------------------------
__global__ void prep_kernel(const float* __restrict__ V, const float* __restrict__ U,
                            float* __restrict__ Vt, unsigned short* __restrict__ Ub,
                            unsigned short* __restrict__ Vtb) {
  int b = blockIdx.x, t = threadIdx.x;
  if (b < 128) {
    __shared__ float tile[64][65];
    int c0 = b * 64;
#pragma unroll
    for (int i = 0; i < 16; ++i) {
      int idx = i * 256 + t;
      int r = idx >> 6, c = idx & 63;
      tile[r][c] = V[r * NDIM + c0 + c];
    }
    __syncthreads();
#pragma unroll
    for (int i = 0; i < 16; ++i) {
      int idx = i * 256 + t;
      int n = idx >> 6, r = idx & 63;
      float v = tile[r][n];
      Vt[(c0 + n) * RANK_C + r]  = v;
      Vtb[(c0 + n) * RANK_C + r] = f2bf(v);
    }
  } else {
    int nt  = 64 * 256;
    int tid = (b - 128) * 256 + t;
    for (int i = tid; i < NDIM * RANK_C; i += nt)
      Ub[i] = f2bf(U[i]);
  }
}

__device__ __forceinline__ void block_reduce_atomic(float v, float* out) {
#pragma unroll
  for (int off = 32; off > 0; off >>= 1) v += __shfl_down(v, off, 64);
  __shared__ float wsum[4];
  int w = threadIdx.x >> 6;
  if ((threadIdx.x & 63) == 0) wsum[w] = v;
  __syncthreads();
  if (threadIdx.x == 0) atomicAdd(out, wsum[0] + wsum[1] + wsum[2] + wsum[3]);
}

// ---------------------------------------------------------------------------
// Fused main kernel, barrier-free S path with a REAL software pipeline.
//   bid % 3 == 0  -> energy gather block (1024 total)
//   else          -> S quadratic-form block: 128x512 chunk of S_U or S_V.
// S path exploits G = A.A^T symmetry: mfma(bfr, af) yields the G^T fragment
// whose C-layout (row=quad*4+reg, col=lcol) pairs element-for-element with a
// dwordx4 row-major load of S -> no LDS transpose, no barriers.
// sv is double-buffered one slab ahead; sched_barrier(0) fences keep the
// scheduler from sinking the loads next to their uses (round-1 failure mode:
// VGPR collapsed to 32, MLP -> 1, BW -> 1.3 TB/s).
// ---------------------------------------------------------------------------
__global__ void __launch_bounds__(256, 4)
main_kernel(const float* __restrict__ vals, const int* __restrict__ rows,
            const int* __restrict__ cols, const float* __restrict__ U,
            const float* __restrict__ sigma, const float* __restrict__ S_U,
            const float* __restrict__ S_V, const float* __restrict__ Vt,
            const unsigned short* __restrict__ Ub,
            const unsigned short* __restrict__ Vtb, float* __restrict__ out) {
  int bid = blockIdx.x;
  int t = threadIdx.x;

  if (bid % 3 == 0) {
    // ---------------- energy term ----------------
    float s2 = sigma[0] * sigma[0];
    float local = 0.f;
    const int estride = E_BLOCKS * 256;
    int n = (bid / 3) * 256 + t;
    if (n < N_OBS_C) {
      int r = rows[n], c = cols[n];
      float v = vals[n];
      for (;;) {
        int nn = n + estride;
        bool more = (nn < N_OBS_C);
        int rn = 0, cn = 0; float vn = 0.f;
        if (more) { rn = rows[nn]; cn = cols[nn]; vn = vals[nn]; }

        const f32x4* up = (const f32x4*)(U  + (size_t)r * RANK_C);
        const f32x4* vp = (const f32x4*)(Vt + (size_t)c * RANK_C);
        float d0 = 0.f, d1 = 0.f, d2 = 0.f, d3 = 0.f;
#pragma unroll
        for (int k = 0; k < 16; k += 4) {
          f32x4 a0 = up[k],     b0 = vp[k];
          f32x4 a1 = up[k + 1], b1 = vp[k + 1];
          f32x4 a2 = up[k + 2], b2 = vp[k + 2];
          f32x4 a3 = up[k + 3], b3 = vp[k + 3];
          d0 += a0[0]*b0[0] + a0[1]*b0[1] + a0[2]*b0[2] + a0[3]*b0[3];
          d1 += a1[0]*b1[0] + a1[1]*b1[1] + a1[2]*b1[2] + a1[3]*b1[3];
          d2 += a2[0]*b2[0] + a2[1]*b2[1] + a2[2]*b2[2] + a2[3]*b2[3];
          d3 += a3[0]*b3[0] + a3[1]*b3[1] + a3[2]*b3[2] + a3[3]*b3[3];
        }
        float e = v - ((d0 + d1) + (d2 + d3));
        local += e * e;
        if (!more) break;
        n = nn; r = rn; c = cn; v = vn;
      }
    }
    local *= 1.0f / (2.0f * s2);
    if (bid == 0 && t == 0) local += (float)N_OBS_C * logf(s2);
    block_reduce_atomic(local, out);
  } else {
    // ---------------- S quadratic-form chunk ----------------
    int sb = (bid / 3) * 2 + (bid % 3) - 1;   // 0..2047
    const float* S; const unsigned short* A;
    if (sb < S_BLOCKS / 2) { S = S_U; A = Ub; }
    else                   { S = S_V; A = Vtb; sb -= S_BLOCKS / 2; }
    int ti0 = (sb >> 4) * 128;   // chunk row origin (64 i-tiles)
    int j0  = (sb & 15) * 512;   // chunk col origin (16 chunks of 512)

    int w = t >> 6, lane = t & 63, quad = lane >> 4, lcol = lane & 15;
    int r0 = ti0 + w * 32;       // this wave's 32-row strip

    // A fragments for the strip rows: hoisted for the whole chunk (16 VGPRs)
    bf16x8 af[2][2];
#pragma unroll
    for (int ti = 0; ti < 2; ++ti)
#pragma unroll
      for (int kh = 0; kh < 2; ++kh)
        af[ti][kh] = *(const bf16x8*)(A + (size_t)(r0 + ti * 16 + lcol) * RANK_C +
                                      kh * 32 + quad * 8);

    // S fragment (ti,tj) of slab hh lives at row (r0+lcol+ti*16),
    // col (j0 + hh*64 + tj*16 + quad*4): two row-base pointers, imm col offsets.
    const float* Sb0 = S + (size_t)(r0 + lcol) * NDIM + j0 + quad * 4;
    const float* Sb1 = Sb0 + (size_t)16 * NDIM;
    const unsigned short* Ab = A + (size_t)(j0 + lcol) * RANK_C + quad * 8;

    f32x4 sv[2][2][4];           // [buf][ti][tj] : 64 VGPRs
    // preload slab 0
#pragma unroll
    for (int tj = 0; tj < 4; ++tj) {
      sv[0][0][tj] = *(const f32x4*)(Sb0 + tj * 16);
      sv[0][1][tj] = *(const f32x4*)(Sb1 + tj * 16);
    }
    __builtin_amdgcn_sched_barrier(0);

    f32x4 sum0 = {0.f, 0.f, 0.f, 0.f}, sum1 = {0.f, 0.f, 0.f, 0.f};

#pragma unroll
    for (int hh = 0; hh < 8; ++hh) {
      const int cur = hh & 1, nxt = cur ^ 1;
      // issue next slab's 8 HBM loads first; fence keeps them batched here
      if (hh < 7) {
#pragma unroll
        for (int tj = 0; tj < 4; ++tj) {
          sv[nxt][0][tj] = *(const f32x4*)(Sb0 + (hh + 1) * 64 + tj * 16);
          sv[nxt][1][tj] = *(const f32x4*)(Sb1 + (hh + 1) * 64 + tj * 16);
        }
      }
      __builtin_amdgcn_sched_barrier(0);
      // compute slab hh in two tj-halves (keeps bfr live-set at 16 VGPRs)
#pragma unroll
      for (int tjh = 0; tjh < 2; ++tjh) {
        bf16x8 bfr[2][2];
#pragma unroll
        for (int tj2 = 0; tj2 < 2; ++tj2)
#pragma unroll
          for (int kh = 0; kh < 2; ++kh)
            bfr[tj2][kh] = *(const bf16x8*)(Ab + (size_t)(hh * 64 + tjh * 32 + tj2 * 16) * RANK_C +
                                            kh * 32);
        __builtin_amdgcn_sched_barrier(0);
#pragma unroll
        for (int tj2 = 0; tj2 < 2; ++tj2) {
          f32x4 z0 = {0.f, 0.f, 0.f, 0.f};
          z0 = __builtin_amdgcn_mfma_f32_16x16x32_bf16(bfr[tj2][0], af[0][0], z0, 0, 0, 0);
          z0 = __builtin_amdgcn_mfma_f32_16x16x32_bf16(bfr[tj2][1], af[0][1], z0, 0, 0, 0);
          sum0 += z0 * sv[cur][0][tjh * 2 + tj2];
          f32x4 z1 = {0.f, 0.f, 0.f, 0.f};
          z1 = __builtin_amdgcn_mfma_f32_16x16x32_bf16(bfr[tj2][0], af[1][0], z1, 0, 0, 0);
          z1 = __builtin_amdgcn_mfma_f32_16x16x32_bf16(bfr[tj2][1], af[1][1], z1, 0, 0, 0);
          sum1 += z1 * sv[cur][1][tjh * 2 + tj2];
        }
      }
    }
    f32x4 sum = sum0 + sum1;
    float p = (sum[0] + sum[1]) + (sum[2] + sum[3]);
    block_reduce_atomic(0.5f * p, out);
  }
}

extern "C" void kernel_launch(void* const* d_in, const int* in_sizes, int n_in,
                              void* d_out, int out_size, void* d_ws, size_t ws_size,
                              hipStream_t stream) {
  const float* vals  = (const float*)d_in[0];
  const int*   rows  = (const int*)  d_in[1];
  const int*   cols  = (const int*)  d_in[2];
  const float* U     = (const float*)d_in[3];
  const float* V     = (const float*)d_in[4];
  const float* sigma = (const float*)d_in[5];
  const float* S_U   = (const float*)d_in[6];
  const float* S_V   = (const float*)d_in[7];
  float* out = (float*)d_out;

  char* ws = (char*)d_ws;
  float*          Vt  = (float*)ws;                                  // 2 MB
  unsigned short* Ub  = (unsigned short*)(ws + 2u * 1024 * 1024);    // 1 MB
  unsigned short* Vtb = (unsigned short*)(ws + 3u * 1024 * 1024);    // 1 MB

  hipMemsetAsync(d_out, 0, sizeof(float), stream);
  prep_kernel<<<192, 256, 0, stream>>>(V, U, Vt, Ub, Vtb);
  // 1024 energy blocks interleaved 1-in-3 with 2048 S-chunk blocks
  main_kernel<<<E_BLOCKS + S_BLOCKS, 256, 0, stream>>>(vals, rows, cols, U, sigma,
                                                       S_U, S_V, Vt, Ub, Vtb, out);
}